// Round 1
// 554.333 us; speedup vs baseline: 1.0171x; 1.0171x over previous
//
#include <hip/hip_runtime.h>
#include <math.h>

#define T 2048
#define B 32
#define N 1024
#define NCHUNK 32           // t-chunks for content partial sums
#define TCHUNK (T / NCHUNK) // 64 timesteps per chunk

__device__ __forceinline__ float fast_tanh(float x) {
    // 1 - 2/(e^{2x}+1): saturates at +/-1, no NaN at overflow.
    // v_rcp_f32 approx is ~1 ulp — far inside the 2e-2 absmax threshold.
    float e = __expf(2.0f * x);
    return 1.0f - 2.0f * __builtin_amdgcn_rcpf(e + 1.0f);
}

__device__ __forceinline__ float wave_reduce_sum(float v) {
    #pragma unroll
    for (int off = 32; off > 0; off >>= 1) v += __shfl_down(v, off, 64);
    return v;
}

// dec[b][i] = sum_j hx[b][j] * Ws_w[i][j] + Ws_b[i]
__global__ void dec_feature_kernel(const float* __restrict__ hx,
                                   const float* __restrict__ Ws_w,
                                   const float* __restrict__ Ws_b,
                                   float* __restrict__ dec) {
    int w = blockIdx.x * 4 + (threadIdx.x >> 6);
    int lane = threadIdx.x & 63;
    int i = w >> 5;
    int b = w & 31;
    const float4* wr = (const float4*)(Ws_w + (size_t)i * N);
    const float4* hr = (const float4*)(hx + (size_t)b * N);
    float acc = 0.f;
    #pragma unroll
    for (int k = 0; k < 4; ++k) {
        float4 a = wr[k * 64 + lane];
        float4 h = hr[k * 64 + lane];
        acc += a.x * h.x + a.y * h.y + a.z * h.z + a.w * h.w;
    }
    acc = wave_reduce_sum(acc);
    if (lane == 0) dec[(size_t)b * N + i] = acc + Ws_b[i];
}

// scores[b][t] = sum_n tanh(ef[t][b][n] + dec[b][n]) * v_w[n] + v_b
// Block = 4 waves, ALL same b (t = tq*4 + wid): dec/v_w rows hit L1 across
// the block instead of 4 distinct rows per block.
__global__ void scores_kernel(const float* __restrict__ ef,
                              const float* __restrict__ dec,
                              const float* __restrict__ v_w,
                              const float* __restrict__ v_b,
                              float* __restrict__ scores) {
    int bx = blockIdx.x;
    int b = bx & 31;
    int tq = bx >> 5;                 // 0 .. T/4-1
    int wid = threadIdx.x >> 6;
    int lane = threadIdx.x & 63;
    int t = tq * 4 + wid;
    const float4* e4 = (const float4*)(ef + ((size_t)t * B + b) * N);
    const float4* d4 = (const float4*)(dec + (size_t)b * N);
    const float4* v4 = (const float4*)v_w;
    float acc = 0.f;
    #pragma unroll
    for (int k = 0; k < 4; ++k) {
        float4 e = e4[k * 64 + lane];
        float4 d = d4[k * 64 + lane];
        float4 v = v4[k * 64 + lane];
        acc += fast_tanh(e.x + d.x) * v.x + fast_tanh(e.y + d.y) * v.y
             + fast_tanh(e.z + d.z) * v.z + fast_tanh(e.w + d.w) * v.w;
    }
    acc = wave_reduce_sum(acc);
    if (lane == 0) scores[(size_t)b * T + t] = acc + v_b[0];
}

// Fused softmax + weighted partial sum (no separate softmax kernel / attn buf):
// each block redundantly computes the row softmax stats from scores (L2-hot,
// 8 KB) then accumulates its 64-timestep chunk of eo.
// partial[chunk][b][n] = sum_{t in chunk} softmax(scores[b])[t]*mask[b][t]*eo[t][b][n]
__global__ void content_partial_kernel(const float* __restrict__ eo,
                                       const float* __restrict__ scores,
                                       const float* __restrict__ mask,
                                       float* __restrict__ partial) {
    int b = blockIdx.y;
    int chunk = blockIdx.x;
    int tid = threadIdx.x;
    int lane = tid & 63, wid = tid >> 6;
    __shared__ float red[4];
    __shared__ float p_sh[TCHUNK];

    // block-wide max over scores[b][:]
    float s[8];
    float m = -1e30f;
    #pragma unroll
    for (int k = 0; k < 8; ++k) {
        s[k] = scores[(size_t)b * T + tid + k * 256];
        m = fmaxf(m, s[k]);
    }
    #pragma unroll
    for (int off = 32; off > 0; off >>= 1) m = fmaxf(m, __shfl_down(m, off, 64));
    if (lane == 0) red[wid] = m;
    __syncthreads();
    m = fmaxf(fmaxf(red[0], red[1]), fmaxf(red[2], red[3]));
    __syncthreads();  // red about to be reused

    // block-wide sum of exp(s - m)  (mask NOT applied to denominator, per ref)
    float sum = 0.f;
    #pragma unroll
    for (int k = 0; k < 8; ++k) sum += __expf(s[k] - m);
    sum = wave_reduce_sum(sum);
    if (lane == 0) red[wid] = sum;
    __syncthreads();
    float invL = __builtin_amdgcn_rcpf(red[0] + red[1] + red[2] + red[3]);

    // attn weights for this chunk only
    if (tid < TCHUNK) {
        int t = chunk * TCHUNK + tid;
        p_sh[tid] = __expf(scores[(size_t)b * T + t] - m) * invL
                  * mask[(size_t)b * T + t];
    }
    __syncthreads();

    const float4* base = (const float4*)eo;
    float4 acc = {0.f, 0.f, 0.f, 0.f};
    #pragma unroll 4
    for (int tt = 0; tt < TCHUNK; ++tt) {
        int t = chunk * TCHUNK + tt;
        float a = p_sh[tt];
        float4 e = base[((size_t)t * B + b) * (N / 4) + tid];
        acc.x += a * e.x; acc.y += a * e.y; acc.z += a * e.z; acc.w += a * e.w;
    }
    ((float4*)partial)[((size_t)chunk * B + b) * (N / 4) + tid] = acc;
}

// content[g] = sum_c partial[c][g]   (g indexes flat B*N)
__global__ void content_reduce_kernel(const float* __restrict__ partial,
                                      float* __restrict__ content) {
    int g = blockIdx.x * 256 + threadIdx.x;  // 0 .. B*N/4-1 (float4 units)
    const float4* p4 = (const float4*)partial;
    float4 acc = {0.f, 0.f, 0.f, 0.f};
    #pragma unroll 8
    for (int c = 0; c < NCHUNK; ++c) {
        float4 v = p4[(size_t)c * (B * N / 4) + g];
        acc.x += v.x; acc.y += v.y; acc.z += v.z; acc.w += v.w;
    }
    ((float4*)content)[g] = acc;
}

// out[b][i] = tanh( dot(content[b], lin_w[i][:N]) + dot(hx[b], lin_w[i][N:]) + lin_b[i] )
__global__ void out_kernel(const float* __restrict__ content,
                           const float* __restrict__ hx,
                           const float* __restrict__ lin_w,
                           const float* __restrict__ lin_b,
                           float* __restrict__ out) {
    int w = blockIdx.x * 4 + (threadIdx.x >> 6);
    int lane = threadIdx.x & 63;
    int i = w >> 5;
    int b = w & 31;
    const float4* wr = (const float4*)(lin_w + (size_t)i * 2 * N);
    const float4* cr = (const float4*)(content + (size_t)b * N);
    const float4* hr = (const float4*)(hx + (size_t)b * N);
    float acc = 0.f;
    #pragma unroll
    for (int k = 0; k < 4; ++k) {
        float4 a = wr[k * 64 + lane];
        float4 c = cr[k * 64 + lane];
        acc += a.x * c.x + a.y * c.y + a.z * c.z + a.w * c.w;
    }
    #pragma unroll
    for (int k = 0; k < 4; ++k) {
        float4 a = wr[256 + k * 64 + lane];
        float4 h = hr[k * 64 + lane];
        acc += a.x * h.x + a.y * h.y + a.z * h.z + a.w * h.w;
    }
    acc = wave_reduce_sum(acc);
    if (lane == 0) out[(size_t)b * N + i] = fast_tanh(acc + lin_b[i]);
}

extern "C" void kernel_launch(void* const* d_in, const int* in_sizes, int n_in,
                              void* d_out, int out_size, void* d_ws, size_t ws_size,
                              hipStream_t stream) {
    const float* hx    = (const float*)d_in[0];
    const float* eo    = (const float*)d_in[1];
    const float* ef    = (const float*)d_in[2];
    const float* mask  = (const float*)d_in[3];
    const float* Ws_w  = (const float*)d_in[4];
    const float* Ws_b  = (const float*)d_in[5];
    const float* v_w   = (const float*)d_in[6];
    const float* v_b   = (const float*)d_in[7];
    const float* lin_w = (const float*)d_in[8];
    const float* lin_b = (const float*)d_in[9];
    float* out = (float*)d_out;

    float* ws      = (float*)d_ws;
    float* dec     = ws;                      // B*N        = 32768 floats
    float* scores  = dec + B * N;             // B*T        = 65536
    float* content = scores + B * T;          // B*N        = 32768
    float* partial = content + B * N;         // NCHUNK*B*N = 1048576 floats (4 MB)

    dec_feature_kernel<<<(B * N) / 4, 256, 0, stream>>>(hx, Ws_w, Ws_b, dec);
    scores_kernel<<<(T * B) / 4, 256, 0, stream>>>(ef, dec, v_w, v_b, scores);
    content_partial_kernel<<<dim3(NCHUNK, B), 256, 0, stream>>>(eo, scores, mask, partial);
    content_reduce_kernel<<<(B * N / 4) / 256, 256, 0, stream>>>(partial, content);
    out_kernel<<<(B * N) / 4, 256, 0, stream>>>(content, hx, lin_w, lin_b, out);
}